// Round 1
// baseline (9006.252 us; speedup 1.0000x reference)
//
#include <hip/hip_runtime.h>

#define NN 20000
#define NE 640000

// ---------------- node encoder: out = LN(x @ w + b) * g + bb ----------------
// one wave per node, lane = output channel
__global__ __launch_bounds__(256) void k_node_enc(
    const float* __restrict__ x, const float* __restrict__ w,
    const float* __restrict__ b, const float* __restrict__ g,
    const float* __restrict__ bb, float* __restrict__ out)
{
    int node = (blockIdx.x * 256 + threadIdx.x) >> 6;
    int lane = threadIdx.x & 63;
    if (node >= NN) return;
    const float* xr = x + (size_t)node * 96;
    float acc = b[lane];
    #pragma unroll
    for (int k = 0; k < 96; ++k) acc = fmaf(xr[k], w[k * 64 + lane], acc);
    float s = acc, s2 = acc * acc;
    #pragma unroll
    for (int off = 32; off; off >>= 1) {
        s  += __shfl_xor(s, off);
        s2 += __shfl_xor(s2, off);
    }
    float mu  = s * 0.015625f;
    float var = s2 * 0.015625f - mu * mu;
    float r   = rsqrtf(var + 1e-5f);
    out[(size_t)node * 64 + lane] = (acc - mu) * r * g[lane] + bb[lane];
}

// ---------------- fused edge pass ----------------
// MODE 0 (conv0): ea = LN(edge_attr @ encw + encb; lng,lnb) computed inline,
//                 msg written to msg_out.
// MODE 1 (conv1): ea = LN(msg0; lng,lnb), msg not stored.
// Then msg = (relu([x_dst|x_src|ea] @ w1 + b1)) @ w2 + b2, and
// atomically accumulate den += exp(msg*t), num += msg*exp(msg*t) at dst.
// LDS is a private column per thread ([64][256] floats) -> no barriers needed.
template <int MODE>
__global__ __launch_bounds__(256, 2) void k_conv_edge(
    const float* __restrict__ xn,      // [NN,64]
    const int*   __restrict__ eidx,    // [2,NE]
    const float* __restrict__ easrc,   // MODE0: edge_attr [NE,16]; MODE1: msg0 [NE,64]
    const float* __restrict__ encw,    // [16,64] (MODE0 only)
    const float* __restrict__ encb,    // [64]    (MODE0 only)
    const float* __restrict__ lng, const float* __restrict__ lnb,
    const float* __restrict__ w1, const float* __restrict__ b1,   // [192,128],[128]
    const float* __restrict__ w2, const float* __restrict__ b2,   // [128,64],[64]
    const float* __restrict__ tp,      // [1]
    float* __restrict__ msg_out,       // MODE0 only [NE,64]
    float* __restrict__ num, float* __restrict__ den)  // [NN,64]
{
    __shared__ float lds[64 * 256];
    const int tid = threadIdx.x;
    const int e = blockIdx.x * 256 + tid;
    if (e >= NE) return;
    const int src = eidx[e];
    const int dst = eidx[NE + e];

    // ---- build ea (raw) into LDS column, accumulating LN stats ----
    float s = 0.f, s2 = 0.f;
    if (MODE == 0) {
        float attr[16];
        const float4* a4 = (const float4*)(easrc + (size_t)e * 16);
        #pragma unroll
        for (int q = 0; q < 4; ++q) {
            float4 v = a4[q];
            attr[4*q+0] = v.x; attr[4*q+1] = v.y; attr[4*q+2] = v.z; attr[4*q+3] = v.w;
        }
        #pragma unroll 1
        for (int c = 0; c < 64; ++c) {
            float a = encb[c];
            #pragma unroll
            for (int k = 0; k < 16; ++k) a = fmaf(attr[k], encw[k * 64 + c], a);
            s += a; s2 = fmaf(a, a, s2);
            lds[c * 256 + tid] = a;
        }
    } else {
        const float4* m4 = (const float4*)(easrc + (size_t)e * 64);
        #pragma unroll 1
        for (int q = 0; q < 16; ++q) {
            float4 v = m4[q];
            s += v.x + v.y + v.z + v.w;
            s2 = fmaf(v.x, v.x, fmaf(v.y, v.y, fmaf(v.z, v.z, fmaf(v.w, v.w, s2))));
            lds[(4*q+0) * 256 + tid] = v.x;
            lds[(4*q+1) * 256 + tid] = v.y;
            lds[(4*q+2) * 256 + tid] = v.z;
            lds[(4*q+3) * 256 + tid] = v.w;
        }
    }
    {
        float mu  = s * 0.015625f;
        float var = s2 * 0.015625f - mu * mu;
        float rs  = rsqrtf(var + 1e-5f);
        #pragma unroll 1
        for (int c = 0; c < 64; ++c) {
            float v = lds[c * 256 + tid];
            lds[c * 256 + tid] = (v - mu) * rs * lng[c] + lnb[c];
        }
    }

    const float4* xd4 = (const float4*)(xn + (size_t)dst * 64);
    const float4* xs4 = (const float4*)(xn + (size_t)src * 64);

    // ---- layer 1: h[j] = relu(b1[j] + sum_k m[k]*w1[k][j]), j split 2x64 ----
    float h0[64], h1[64];
    auto layer1_half = [&](float (&h)[64], int jc) {
        #pragma unroll
        for (int j = 0; j < 64; ++j) h[j] = b1[jc + j];
        #pragma unroll 1
        for (int k4 = 0; k4 < 16; ++k4) {          // k = 0..63 : x_dst
            float4 v = xd4[k4];
            const float* wr = w1 + (size_t)(k4 * 4) * 128 + jc;
            #pragma unroll
            for (int j = 0; j < 64; ++j) h[j] = fmaf(v.x, wr[j], h[j]);
            #pragma unroll
            for (int j = 0; j < 64; ++j) h[j] = fmaf(v.y, wr[128 + j], h[j]);
            #pragma unroll
            for (int j = 0; j < 64; ++j) h[j] = fmaf(v.z, wr[256 + j], h[j]);
            #pragma unroll
            for (int j = 0; j < 64; ++j) h[j] = fmaf(v.w, wr[384 + j], h[j]);
        }
        #pragma unroll 1
        for (int k4 = 0; k4 < 16; ++k4) {          // k = 64..127 : x_src
            float4 v = xs4[k4];
            const float* wr = w1 + (size_t)(64 + k4 * 4) * 128 + jc;
            #pragma unroll
            for (int j = 0; j < 64; ++j) h[j] = fmaf(v.x, wr[j], h[j]);
            #pragma unroll
            for (int j = 0; j < 64; ++j) h[j] = fmaf(v.y, wr[128 + j], h[j]);
            #pragma unroll
            for (int j = 0; j < 64; ++j) h[j] = fmaf(v.z, wr[256 + j], h[j]);
            #pragma unroll
            for (int j = 0; j < 64; ++j) h[j] = fmaf(v.w, wr[384 + j], h[j]);
        }
        #pragma unroll 1
        for (int k = 0; k < 64; ++k) {             // k = 128..191 : ea (LDS)
            float m = lds[k * 256 + tid];
            const float* wr = w1 + (size_t)(128 + k) * 128 + jc;
            #pragma unroll
            for (int j = 0; j < 64; ++j) h[j] = fmaf(m, wr[j], h[j]);
        }
        #pragma unroll
        for (int j = 0; j < 64; ++j) h[j] = fmaxf(h[j], 0.f);
    };
    layer1_half(h0, 0);
    layer1_half(h1, 64);

    // ---- layer 2: msg[c] = b2[c] + sum_j h[j]*w2[j][c] ----
    // h goes through LDS so the j-loop can stay rolled (no dyn reg indexing).
    float msg[64];
    #pragma unroll
    for (int c = 0; c < 64; ++c) msg[c] = b2[c];
    #pragma unroll
    for (int j = 0; j < 64; ++j) lds[j * 256 + tid] = h0[j];
    #pragma unroll 1
    for (int j = 0; j < 64; ++j) {
        float hj = lds[j * 256 + tid];
        const float* w2r = w2 + (size_t)j * 64;
        #pragma unroll
        for (int c = 0; c < 64; ++c) msg[c] = fmaf(hj, w2r[c], msg[c]);
    }
    #pragma unroll
    for (int j = 0; j < 64; ++j) lds[j * 256 + tid] = h1[j];
    #pragma unroll 1
    for (int j = 0; j < 64; ++j) {
        float hj = lds[j * 256 + tid];
        const float* w2r = w2 + (size_t)(64 + j) * 64;
        #pragma unroll
        for (int c = 0; c < 64; ++c) msg[c] = fmaf(hj, w2r[c], msg[c]);
    }

    if (MODE == 0) {
        float4* mo = (float4*)(msg_out + (size_t)e * 64);
        #pragma unroll
        for (int q = 0; q < 16; ++q)
            mo[q] = make_float4(msg[4*q], msg[4*q+1], msg[4*q+2], msg[4*q+3]);
    }

    // ---- softmax accumulation (no max pass: exp args are O(4), safe in fp32) ----
    #pragma unroll
    for (int c = 0; c < 64; ++c) lds[c * 256 + tid] = msg[c];
    const float t = tp[0];
    float* drow = den + (size_t)dst * 64;
    float* nrow = num + (size_t)dst * 64;
    #pragma unroll 1
    for (int c = 0; c < 64; ++c) {
        float m  = lds[c * 256 + tid];
        float ex = __expf(m * t);
        atomicAdd(drow + c, ex);
        atomicAdd(nrow + c, m * ex);
    }
}

// ---------------- conv0 finalize: x1 = num/den + xenc@wr; h = relu(LN(x1)) ----
__global__ __launch_bounds__(256) void k_finalize0(
    const float* __restrict__ xenc, const float* __restrict__ num,
    const float* __restrict__ den, const float* __restrict__ wr,
    const float* __restrict__ g, const float* __restrict__ b,
    float* __restrict__ x1, float* __restrict__ hout)
{
    int node = (blockIdx.x * 256 + threadIdx.x) >> 6;
    int lane = threadIdx.x & 63;
    if (node >= NN) return;
    const float* xr = xenc + (size_t)node * 64;
    float root = 0.f;
    #pragma unroll
    for (int k = 0; k < 64; ++k) root = fmaf(xr[k], wr[k * 64 + lane], root);
    size_t idx = (size_t)node * 64 + lane;
    float d = den[idx];
    float v = root + (d > 0.f ? num[idx] / d : 0.f);
    x1[idx] = v;
    float s = v, s2 = v * v;
    #pragma unroll
    for (int off = 32; off; off >>= 1) {
        s  += __shfl_xor(s, off);
        s2 += __shfl_xor(s2, off);
    }
    float mu  = s * 0.015625f;
    float var = s2 * 0.015625f - mu * mu;
    float r   = rsqrtf(var + 1e-5f);
    hout[idx] = fmaxf((v - mu) * r * g[lane] + b[lane], 0.f);
}

// ---------------- final: out = x1 + num1/den1 + h@wr ----------------
__global__ __launch_bounds__(256) void k_final(
    const float* __restrict__ x1, const float* __restrict__ hbuf,
    const float* __restrict__ num, const float* __restrict__ den,
    const float* __restrict__ wr, float* __restrict__ out)
{
    int node = (blockIdx.x * 256 + threadIdx.x) >> 6;
    int lane = threadIdx.x & 63;
    if (node >= NN) return;
    const float* hr = hbuf + (size_t)node * 64;
    float root = 0.f;
    #pragma unroll
    for (int k = 0; k < 64; ++k) root = fmaf(hr[k], wr[k * 64 + lane], root);
    size_t idx = (size_t)node * 64 + lane;
    float d = den[idx];
    out[idx] = x1[idx] + root + (d > 0.f ? num[idx] / d : 0.f);
}

extern "C" void kernel_launch(void* const* d_in, const int* in_sizes, int n_in,
                              void* d_out, int out_size, void* d_ws, size_t ws_size,
                              hipStream_t stream)
{
    const float* x       = (const float*)d_in[0];
    const int*   eidx    = (const int*)  d_in[1];
    const float* eattr   = (const float*)d_in[2];
    const float* enc_w   = (const float*)d_in[3];
    const float* enc_b   = (const float*)d_in[4];
    const float* enc_g   = (const float*)d_in[5];
    const float* enc_bb  = (const float*)d_in[6];
    const float* eenc_w  = (const float*)d_in[7];
    const float* eenc_b  = (const float*)d_in[8];
    const float* eenc_g  = (const float*)d_in[9];
    const float* eenc_bb = (const float*)d_in[10];
    const float* c0_w1   = (const float*)d_in[11];
    const float* c0_b1   = (const float*)d_in[12];
    const float* c0_w2   = (const float*)d_in[13];
    const float* c0_b2   = (const float*)d_in[14];
    const float* c0_wr   = (const float*)d_in[15];
    const float* c0_t    = (const float*)d_in[16];
    const float* l1_g    = (const float*)d_in[17];
    const float* l1_b    = (const float*)d_in[18];
    const float* l1_eg   = (const float*)d_in[19];
    const float* l1_eb   = (const float*)d_in[20];
    const float* c1_w1   = (const float*)d_in[21];
    const float* c1_b1   = (const float*)d_in[22];
    const float* c1_w2   = (const float*)d_in[23];
    const float* c1_b2   = (const float*)d_in[24];
    const float* c1_wr   = (const float*)d_in[25];
    const float* c1_t    = (const float*)d_in[26];

    const size_t NV = (size_t)NN * 64;
    float* ws   = (float*)d_ws;
    float* num0 = ws;
    float* den0 = num0 + NV;
    float* num1 = den0 + NV;
    float* den1 = num1 + NV;
    float* xenc = den1 + NV;
    float* hbuf = xenc + NV;
    float* x1   = hbuf + NV;
    float* msg0 = x1   + NV;          // [NE,64] = 163.84 MB
    float* out  = (float*)d_out;

    hipMemsetAsync(num0, 0, 4 * NV * sizeof(float), stream);

    k_node_enc<<<NN / 4, 256, 0, stream>>>(x, enc_w, enc_b, enc_g, enc_bb, xenc);

    k_conv_edge<0><<<NE / 256, 256, 0, stream>>>(
        xenc, eidx, eattr, eenc_w, eenc_b, eenc_g, eenc_bb,
        c0_w1, c0_b1, c0_w2, c0_b2, c0_t, msg0, num0, den0);

    k_finalize0<<<NN / 4, 256, 0, stream>>>(xenc, num0, den0, c0_wr, l1_g, l1_b, x1, hbuf);

    k_conv_edge<1><<<NE / 256, 256, 0, stream>>>(
        hbuf, eidx, msg0, nullptr, nullptr, l1_eg, l1_eb,
        c1_w1, c1_b1, c1_w2, c1_b2, c1_t, nullptr, num1, den1);

    k_final<<<NN / 4, 256, 0, stream>>>(x1, hbuf, num1, den1, c1_wr, out);
}

// Round 2
// 2423.365 us; speedup vs baseline: 3.7164x; 3.7164x over previous
//
#include <hip/hip_runtime.h>

#define NN 20000
#define NE 640000

// ---------------- node encoder: out = LN(x @ w + b) * g + bb ----------------
__global__ __launch_bounds__(256) void k_node_enc(
    const float* __restrict__ x, const float* __restrict__ w,
    const float* __restrict__ b, const float* __restrict__ g,
    const float* __restrict__ bb, float* __restrict__ out)
{
    int node = (blockIdx.x * 256 + threadIdx.x) >> 6;
    int lane = threadIdx.x & 63;
    if (node >= NN) return;
    const float* xr = x + (size_t)node * 96;
    float acc = b[lane];
    #pragma unroll
    for (int k = 0; k < 96; ++k) acc = fmaf(xr[k], w[k * 64 + lane], acc);
    float s = acc, s2 = acc * acc;
    #pragma unroll
    for (int off = 32; off; off >>= 1) {
        s  += __shfl_xor(s, off);
        s2 += __shfl_xor(s2, off);
    }
    float mu  = s * 0.015625f;
    float var = s2 * 0.015625f - mu * mu;
    float r   = rsqrtf(var + 1e-5f);
    out[(size_t)node * 64 + lane] = (acc - mu) * r * g[lane] + bb[lane];
}

// ---------------- CSR build ----------------
__global__ __launch_bounds__(256) void k_degree(
    const int* __restrict__ eidx, int* __restrict__ deg)
{
    int e = blockIdx.x * 256 + threadIdx.x;
    if (e < NE) atomicAdd(&deg[eidx[NE + e]], 1);
}

// single-block exclusive scan over NN degrees -> row_ptr, cursor
__global__ __launch_bounds__(1024) void k_scan(
    const int* __restrict__ deg, int* __restrict__ row_ptr, int* __restrict__ cursor)
{
    __shared__ int sums[1024];
    const int T = 1024, CHUNK = (NN + 1023) / 1024;  // 20
    int tid = threadIdx.x;
    int base = tid * CHUNK;
    int local = 0;
    for (int i = 0; i < CHUNK; ++i) {
        int idx = base + i;
        if (idx < NN) local += deg[idx];
    }
    sums[tid] = local;
    __syncthreads();
    for (int off = 1; off < T; off <<= 1) {
        int v = (tid >= off) ? sums[tid - off] : 0;
        __syncthreads();
        sums[tid] += v;
        __syncthreads();
    }
    int run = (tid == 0) ? 0 : sums[tid - 1];
    for (int i = 0; i < CHUNK; ++i) {
        int idx = base + i;
        if (idx < NN) {
            row_ptr[idx] = run;
            cursor[idx]  = run;
            run += deg[idx];
        }
    }
    if (tid == T - 1) row_ptr[NN] = run;
}

__global__ __launch_bounds__(256) void k_scatter(
    const int* __restrict__ eidx, int* __restrict__ cursor, int* __restrict__ eord)
{
    int e = blockIdx.x * 256 + threadIdx.x;
    if (e < NE) {
        int p = atomicAdd(&cursor[eidx[NE + e]], 1);
        eord[p] = e;
    }
}

// ---------------- fused edge pass (no atomics: just writes msg rows) --------
// MODE 0 (conv0): ea = LN(edge_attr @ encw + encb), msg -> msg_out.
// MODE 1 (conv1): ea = LN(msg0 row), msg overwrites the same row (in place).
template <int MODE>
__global__ __launch_bounds__(256, 2) void k_conv_edge(
    const float* __restrict__ xn,      // [NN,64]
    const int*   __restrict__ eidx,    // [2,NE]
    const float* easrc,                // MODE0: edge_attr [NE,16]; MODE1: msg [NE,64]
    const float* __restrict__ encw,    // [16,64] (MODE0 only)
    const float* __restrict__ encb,    // [64]    (MODE0 only)
    const float* __restrict__ lng, const float* __restrict__ lnb,
    const float* __restrict__ w1, const float* __restrict__ b1,   // [192,128],[128]
    const float* __restrict__ w2, const float* __restrict__ b2,   // [128,64],[64]
    float* msg_out)                    // [NE,64]
{
    __shared__ float lds[64 * 256];
    const int tid = threadIdx.x;
    const int e = blockIdx.x * 256 + tid;
    if (e >= NE) return;
    const int src = eidx[e];
    const int dst = eidx[NE + e];

    // ---- build ea (raw) into LDS column, accumulating LN stats ----
    float s = 0.f, s2 = 0.f;
    if (MODE == 0) {
        float attr[16];
        const float4* a4 = (const float4*)(easrc + (size_t)e * 16);
        #pragma unroll
        for (int q = 0; q < 4; ++q) {
            float4 v = a4[q];
            attr[4*q+0] = v.x; attr[4*q+1] = v.y; attr[4*q+2] = v.z; attr[4*q+3] = v.w;
        }
        #pragma unroll 1
        for (int c = 0; c < 64; ++c) {
            float a = encb[c];
            #pragma unroll
            for (int k = 0; k < 16; ++k) a = fmaf(attr[k], encw[k * 64 + c], a);
            s += a; s2 = fmaf(a, a, s2);
            lds[c * 256 + tid] = a;
        }
    } else {
        const float4* m4 = (const float4*)(easrc + (size_t)e * 64);
        #pragma unroll 1
        for (int q = 0; q < 16; ++q) {
            float4 v = m4[q];
            s += v.x + v.y + v.z + v.w;
            s2 = fmaf(v.x, v.x, fmaf(v.y, v.y, fmaf(v.z, v.z, fmaf(v.w, v.w, s2))));
            lds[(4*q+0) * 256 + tid] = v.x;
            lds[(4*q+1) * 256 + tid] = v.y;
            lds[(4*q+2) * 256 + tid] = v.z;
            lds[(4*q+3) * 256 + tid] = v.w;
        }
    }
    {
        float mu  = s * 0.015625f;
        float var = s2 * 0.015625f - mu * mu;
        float rs  = rsqrtf(var + 1e-5f);
        #pragma unroll 1
        for (int c = 0; c < 64; ++c) {
            float v = lds[c * 256 + tid];
            lds[c * 256 + tid] = (v - mu) * rs * lng[c] + lnb[c];
        }
    }

    const float4* xd4 = (const float4*)(xn + (size_t)dst * 64);
    const float4* xs4 = (const float4*)(xn + (size_t)src * 64);

    // ---- layer 1: h[j] = relu(b1[j] + sum_k m[k]*w1[k][j]), j split 2x64 ----
    float h0[64], h1[64];
    auto layer1_half = [&](float (&h)[64], int jc) {
        #pragma unroll
        for (int j = 0; j < 64; ++j) h[j] = b1[jc + j];
        #pragma unroll 1
        for (int k4 = 0; k4 < 16; ++k4) {          // k = 0..63 : x_dst
            float4 v = xd4[k4];
            const float* wr = w1 + (size_t)(k4 * 4) * 128 + jc;
            #pragma unroll
            for (int j = 0; j < 64; ++j) h[j] = fmaf(v.x, wr[j], h[j]);
            #pragma unroll
            for (int j = 0; j < 64; ++j) h[j] = fmaf(v.y, wr[128 + j], h[j]);
            #pragma unroll
            for (int j = 0; j < 64; ++j) h[j] = fmaf(v.z, wr[256 + j], h[j]);
            #pragma unroll
            for (int j = 0; j < 64; ++j) h[j] = fmaf(v.w, wr[384 + j], h[j]);
        }
        #pragma unroll 1
        for (int k4 = 0; k4 < 16; ++k4) {          // k = 64..127 : x_src
            float4 v = xs4[k4];
            const float* wr = w1 + (size_t)(64 + k4 * 4) * 128 + jc;
            #pragma unroll
            for (int j = 0; j < 64; ++j) h[j] = fmaf(v.x, wr[j], h[j]);
            #pragma unroll
            for (int j = 0; j < 64; ++j) h[j] = fmaf(v.y, wr[128 + j], h[j]);
            #pragma unroll
            for (int j = 0; j < 64; ++j) h[j] = fmaf(v.z, wr[256 + j], h[j]);
            #pragma unroll
            for (int j = 0; j < 64; ++j) h[j] = fmaf(v.w, wr[384 + j], h[j]);
        }
        #pragma unroll 1
        for (int k = 0; k < 64; ++k) {             // k = 128..191 : ea (LDS)
            float m = lds[k * 256 + tid];
            const float* wr = w1 + (size_t)(128 + k) * 128 + jc;
            #pragma unroll
            for (int j = 0; j < 64; ++j) h[j] = fmaf(m, wr[j], h[j]);
        }
        #pragma unroll
        for (int j = 0; j < 64; ++j) h[j] = fmaxf(h[j], 0.f);
    };
    layer1_half(h0, 0);
    layer1_half(h1, 64);

    // ---- layer 2: msg[c] = b2[c] + sum_j h[j]*w2[j][c] ----
    float msg[64];
    #pragma unroll
    for (int c = 0; c < 64; ++c) msg[c] = b2[c];
    #pragma unroll
    for (int j = 0; j < 64; ++j) lds[j * 256 + tid] = h0[j];
    #pragma unroll 1
    for (int j = 0; j < 64; ++j) {
        float hj = lds[j * 256 + tid];
        const float* w2r = w2 + (size_t)j * 64;
        #pragma unroll
        for (int c = 0; c < 64; ++c) msg[c] = fmaf(hj, w2r[c], msg[c]);
    }
    #pragma unroll
    for (int j = 0; j < 64; ++j) lds[j * 256 + tid] = h1[j];
    #pragma unroll 1
    for (int j = 0; j < 64; ++j) {
        float hj = lds[j * 256 + tid];
        const float* w2r = w2 + (size_t)(64 + j) * 64;
        #pragma unroll
        for (int c = 0; c < 64; ++c) msg[c] = fmaf(hj, w2r[c], msg[c]);
    }

    float4* mo = (float4*)(msg_out + (size_t)e * 64);
    #pragma unroll
    for (int q = 0; q < 16; ++q)
        mo[q] = make_float4(msg[4*q], msg[4*q+1], msg[4*q+2], msg[4*q+3]);
}

// ---------------- gather0: agg + root -> x1; h = relu(LN(x1)) ----------------
__global__ __launch_bounds__(256) void k_gather0(
    const float* __restrict__ xenc, const float* __restrict__ msg,
    const int* __restrict__ row_ptr, const int* __restrict__ eord,
    const float* __restrict__ wr, const float* __restrict__ g,
    const float* __restrict__ b, const float* __restrict__ tp,
    float* __restrict__ x1, float* __restrict__ hout)
{
    int node = (blockIdx.x * 256 + threadIdx.x) >> 6;
    int lane = threadIdx.x & 63;
    if (node >= NN) return;
    const float* xr = xenc + (size_t)node * 64;
    float root = 0.f;
    #pragma unroll
    for (int k = 0; k < 64; ++k) root = fmaf(xr[k], wr[k * 64 + lane], root);
    const float t = tp[0];
    int beg = row_ptr[node], end = row_ptr[node + 1];
    float den = 0.f, num = 0.f;
    for (int i = beg; i < end; ++i) {
        int e = eord[i];
        float m = msg[(size_t)e * 64 + lane];
        float ex = __expf(m * t);
        den += ex;
        num = fmaf(m, ex, num);
    }
    float v = root + (den > 0.f ? num / den : 0.f);
    size_t idx = (size_t)node * 64 + lane;
    x1[idx] = v;
    float s = v, s2 = v * v;
    #pragma unroll
    for (int off = 32; off; off >>= 1) {
        s  += __shfl_xor(s, off);
        s2 += __shfl_xor(s2, off);
    }
    float mu  = s * 0.015625f;
    float var = s2 * 0.015625f - mu * mu;
    float r   = rsqrtf(var + 1e-5f);
    hout[idx] = fmaxf((v - mu) * r * g[lane] + b[lane], 0.f);
}

// ---------------- gather1: out = x1 + root(h) + agg(msg1) ----------------
__global__ __launch_bounds__(256) void k_gather1(
    const float* __restrict__ x1, const float* __restrict__ hbuf,
    const float* __restrict__ msg,
    const int* __restrict__ row_ptr, const int* __restrict__ eord,
    const float* __restrict__ wr, const float* __restrict__ tp,
    float* __restrict__ out)
{
    int node = (blockIdx.x * 256 + threadIdx.x) >> 6;
    int lane = threadIdx.x & 63;
    if (node >= NN) return;
    const float* hr = hbuf + (size_t)node * 64;
    float root = 0.f;
    #pragma unroll
    for (int k = 0; k < 64; ++k) root = fmaf(hr[k], wr[k * 64 + lane], root);
    const float t = tp[0];
    int beg = row_ptr[node], end = row_ptr[node + 1];
    float den = 0.f, num = 0.f;
    for (int i = beg; i < end; ++i) {
        int e = eord[i];
        float m = msg[(size_t)e * 64 + lane];
        float ex = __expf(m * t);
        den += ex;
        num = fmaf(m, ex, num);
    }
    size_t idx = (size_t)node * 64 + lane;
    out[idx] = x1[idx] + root + (den > 0.f ? num / den : 0.f);
}

extern "C" void kernel_launch(void* const* d_in, const int* in_sizes, int n_in,
                              void* d_out, int out_size, void* d_ws, size_t ws_size,
                              hipStream_t stream)
{
    const float* x       = (const float*)d_in[0];
    const int*   eidx    = (const int*)  d_in[1];
    const float* eattr   = (const float*)d_in[2];
    const float* enc_w   = (const float*)d_in[3];
    const float* enc_b   = (const float*)d_in[4];
    const float* enc_g   = (const float*)d_in[5];
    const float* enc_bb  = (const float*)d_in[6];
    const float* eenc_w  = (const float*)d_in[7];
    const float* eenc_b  = (const float*)d_in[8];
    const float* eenc_g  = (const float*)d_in[9];
    const float* eenc_bb = (const float*)d_in[10];
    const float* c0_w1   = (const float*)d_in[11];
    const float* c0_b1   = (const float*)d_in[12];
    const float* c0_w2   = (const float*)d_in[13];
    const float* c0_b2   = (const float*)d_in[14];
    const float* c0_wr   = (const float*)d_in[15];
    const float* c0_t    = (const float*)d_in[16];
    const float* l1_g    = (const float*)d_in[17];
    const float* l1_b    = (const float*)d_in[18];
    const float* l1_eg   = (const float*)d_in[19];
    const float* l1_eb   = (const float*)d_in[20];
    const float* c1_w1   = (const float*)d_in[21];
    const float* c1_b1   = (const float*)d_in[22];
    const float* c1_w2   = (const float*)d_in[23];
    const float* c1_b2   = (const float*)d_in[24];
    const float* c1_wr   = (const float*)d_in[25];
    const float* c1_t    = (const float*)d_in[26];

    const size_t NV = (size_t)NN * 64;
    float* ws   = (float*)d_ws;
    float* xenc = ws;                       // NV
    float* hbuf = xenc + NV;                // NV
    float* x1   = hbuf + NV;                // NV
    int*   deg     = (int*)(x1 + NV);       // NN
    int*   row_ptr = deg + NN;              // NN+16 (padded for alignment)
    int*   cursor  = row_ptr + NN + 16;     // NN
    int*   eord    = cursor + NN;           // NE
    float* msg     = (float*)(eord + NE);   // NE*64  (163.84 MB), 16B-aligned
    float* out  = (float*)d_out;

    hipMemsetAsync(deg, 0, NN * sizeof(int), stream);

    k_node_enc<<<NN / 4, 256, 0, stream>>>(x, enc_w, enc_b, enc_g, enc_bb, xenc);
    k_degree <<<NE / 256, 256, 0, stream>>>(eidx, deg);
    k_scan   <<<1, 1024, 0, stream>>>(deg, row_ptr, cursor);
    k_scatter<<<NE / 256, 256, 0, stream>>>(eidx, cursor, eord);

    k_conv_edge<0><<<NE / 256, 256, 0, stream>>>(
        xenc, eidx, eattr, eenc_w, eenc_b, eenc_g, eenc_bb,
        c0_w1, c0_b1, c0_w2, c0_b2, msg);

    k_gather0<<<NN / 4, 256, 0, stream>>>(
        xenc, msg, row_ptr, eord, c0_wr, l1_g, l1_b, c0_t, x1, hbuf);

    k_conv_edge<1><<<NE / 256, 256, 0, stream>>>(
        hbuf, eidx, msg, nullptr, nullptr, l1_eg, l1_eb,
        c1_w1, c1_b1, c1_w2, c1_b2, msg);

    k_gather1<<<NN / 4, 256, 0, stream>>>(
        x1, hbuf, msg, row_ptr, eord, c1_wr, c1_t, out);
}

// Round 3
// 1040.142 us; speedup vs baseline: 8.6587x; 2.3298x over previous
//
#include <hip/hip_runtime.h>

#define NN 20000
#define NE 640000
#define NTILES (NE / 64)
#define HSTR 136   // h_lds row stride in shorts (padded: 2-way-max bank aliasing)

typedef float f32x4 __attribute__((ext_vector_type(4)));
typedef short short8 __attribute__((ext_vector_type(8)));
union S8I4 { int4 i; short8 s; };

#define MFMA(a, b, c) __builtin_amdgcn_mfma_f32_16x16x32_bf16((a), (b), (c), 0, 0, 0)

__device__ __forceinline__ short f2bf(float f) {
    unsigned u = __float_as_uint(f);
    u = (u + 0x7FFFu + ((u >> 16) & 1u)) >> 16;   // RNE
    return (short)u;
}
__device__ __forceinline__ float bf2f(short s) {
    return __uint_as_float(((unsigned)(unsigned short)s) << 16);
}

// ---------------- weight pre-pack into MFMA B-fragment order ----------------
// B-frag storage: frag f = kt*(N/16)+nt; lane l holds 8 shorts = B[k][n],
// k = kt*32 + (l>>4)*8 + j, n = nt*16 + (l&15).  24576 threads, idx = element.
__global__ __launch_bounds__(256) void k_prep_w(
    const float* __restrict__ w1a, const float* __restrict__ w2a,
    const float* __restrict__ w1b, const float* __restrict__ w2b,
    short* __restrict__ p1a, short* __restrict__ p2a,
    short* __restrict__ p1b, short* __restrict__ p2b)
{
    int idx = blockIdx.x * 256 + threadIdx.x;      // 0..24575
    {
        int f = idx >> 9, l = (idx >> 3) & 63, j = idx & 7;
        int kt = f >> 3, nt = f & 7;
        int k = kt * 32 + ((l >> 4) << 3) + j;
        int n = (nt << 4) + (l & 15);
        p1a[idx] = f2bf(w1a[k * 128 + n]);
        p1b[idx] = f2bf(w1b[k * 128 + n]);
    }
    if (idx < 8192) {
        int f = idx >> 9, l = (idx >> 3) & 63, j = idx & 7;
        int kt = f >> 2, nt = f & 3;
        int k = kt * 32 + ((l >> 4) << 3) + j;
        int n = (nt << 4) + (l & 15);
        p2a[idx] = f2bf(w2a[k * 64 + n]);
        p2b[idx] = f2bf(w2b[k * 64 + n]);
    }
}

// ---------------- node encoder: xenc fp32 + xb bf16 ----------------
__global__ __launch_bounds__(256) void k_node_enc(
    const float* __restrict__ x, const float* __restrict__ w,
    const float* __restrict__ b, const float* __restrict__ g,
    const float* __restrict__ bb, float* __restrict__ out, short* __restrict__ outb)
{
    int node = (blockIdx.x * 256 + threadIdx.x) >> 6;
    int lane = threadIdx.x & 63;
    if (node >= NN) return;
    const float* xr = x + (size_t)node * 96;
    float acc = b[lane];
    #pragma unroll
    for (int k = 0; k < 96; ++k) acc = fmaf(xr[k], w[k * 64 + lane], acc);
    float s = acc, s2 = acc * acc;
    #pragma unroll
    for (int off = 32; off; off >>= 1) { s += __shfl_xor(s, off); s2 += __shfl_xor(s2, off); }
    float mu = s * 0.015625f, var = s2 * 0.015625f - mu * mu;
    float r = rsqrtf(var + 1e-5f);
    float v = (acc - mu) * r * g[lane] + bb[lane];
    size_t idx = (size_t)node * 64 + lane;
    out[idx] = v;
    outb[idx] = f2bf(v);
}

// ---------------- edge encoder: eab = bf16(LN(edge_attr @ w + b)) ----------------
__global__ __launch_bounds__(256) void k_edge_enc(
    const float* __restrict__ ea, const float* __restrict__ w,
    const float* __restrict__ b, const float* __restrict__ g,
    const float* __restrict__ bb, short* __restrict__ out)
{
    int e = (blockIdx.x * 256 + threadIdx.x) >> 6;
    int lane = threadIdx.x & 63;
    if (e >= NE) return;
    const float* ar = ea + (size_t)e * 16;
    float acc = b[lane];
    #pragma unroll
    for (int k = 0; k < 16; ++k) acc = fmaf(ar[k], w[k * 64 + lane], acc);
    float s = acc, s2 = acc * acc;
    #pragma unroll
    for (int off = 32; off; off >>= 1) { s += __shfl_xor(s, off); s2 += __shfl_xor(s2, off); }
    float mu = s * 0.015625f, var = s2 * 0.015625f - mu * mu;
    float r = rsqrtf(var + 1e-5f);
    out[(size_t)e * 64 + lane] = f2bf((acc - mu) * r * g[lane] + bb[lane]);
}

// ---------------- CSR build ----------------
__global__ __launch_bounds__(256) void k_degree(
    const int* __restrict__ eidx, int* __restrict__ deg)
{
    int e = blockIdx.x * 256 + threadIdx.x;
    if (e < NE) atomicAdd(&deg[eidx[NE + e]], 1);
}

__global__ __launch_bounds__(1024) void k_scan(
    const int* __restrict__ deg, int* __restrict__ row_ptr, int* __restrict__ cursor)
{
    __shared__ int sums[1024];
    const int T = 1024, CHUNK = (NN + 1023) / 1024;
    int tid = threadIdx.x;
    int base = tid * CHUNK;
    int local = 0;
    for (int i = 0; i < CHUNK; ++i) { int idx = base + i; if (idx < NN) local += deg[idx]; }
    sums[tid] = local;
    __syncthreads();
    for (int off = 1; off < T; off <<= 1) {
        int v = (tid >= off) ? sums[tid - off] : 0;
        __syncthreads();
        sums[tid] += v;
        __syncthreads();
    }
    int run = (tid == 0) ? 0 : sums[tid - 1];
    for (int i = 0; i < CHUNK; ++i) {
        int idx = base + i;
        if (idx < NN) { row_ptr[idx] = run; cursor[idx] = run; run += deg[idx]; }
    }
    if (tid == T - 1) row_ptr[NN] = run;
}

__global__ __launch_bounds__(256) void k_scatter(
    const int* __restrict__ eidx, int* __restrict__ cursor, int* __restrict__ eord)
{
    int e = blockIdx.x * 256 + threadIdx.x;
    if (e < NE) { int p = atomicAdd(&cursor[eidx[NE + e]], 1); eord[p] = e; }
}

// ---------------- MFMA edge conv ----------------
// Block: 64 edges, 4 waves. Wave w: layer1 N-strip [w*32, w*32+32), layer2 strip
// [w*16, w*16+16). MODE0: ea from eab (pre-LN'd). MODE1: ea = LN(msgb row) in-reg,
// msg overwrites msgb in place (block owns its rows; reads precede barrier).
template <int MODE>
__global__ __launch_bounds__(256, 2) void k_conv_mfma(
    const short* __restrict__ xb,      // [NN,64] bf16 node features
    const int*   __restrict__ eidx,    // [2,NE]
    const short* __restrict__ eamsg,   // MODE0: eab; MODE1: msgb
    const float* __restrict__ lng, const float* __restrict__ lnb,  // MODE1 only
    const short* __restrict__ w1p, const float* __restrict__ b1,
    const short* __restrict__ w2p, const float* __restrict__ b2,
    short* __restrict__ msgb)          // [NE,64] bf16 out
{
    __shared__ short h_lds[64 * HSTR];
    const int tid  = threadIdx.x;
    const int wave = tid >> 6;
    const int lane = tid & 63;
    const int quad = lane >> 4;
    const int l15  = lane & 15;
    const int qoff = quad * 8;

    // persistent B fragments (registers)
    short8 B1[6][2], B2[4];
    {
        const int4* p = (const int4*)w1p;
        #pragma unroll
        for (int kt = 0; kt < 6; ++kt)
            #pragma unroll
            for (int nf = 0; nf < 2; ++nf) {
                S8I4 u; u.i = p[(kt * 8 + wave * 2 + nf) * 64 + lane];
                B1[kt][nf] = u.s;
            }
        const int4* q = (const int4*)w2p;
        #pragma unroll
        for (int kt = 0; kt < 4; ++kt) {
            S8I4 u; u.i = q[(kt * 4 + wave) * 64 + lane];
            B2[kt] = u.s;
        }
    }
    const float b1v0 = b1[wave * 32 + l15];
    const float b1v1 = b1[wave * 32 + 16 + l15];
    const float b2v  = b2[wave * 16 + l15];

    float lnGv[16], lnBv[16];
    if (MODE == 1) {
        #pragma unroll
        for (int j = 0; j < 8; ++j) {
            lnGv[j]     = lng[qoff + j];      lnGv[8 + j] = lng[32 + qoff + j];
            lnBv[j]     = lnb[qoff + j];      lnBv[8 + j] = lnb[32 + qoff + j];
        }
    }

    for (int t = blockIdx.x; t < NTILES; t += gridDim.x) {
        const int ebase = t * 64;
        __syncthreads();   // h_lds reuse guard (and MODE1 in-place read/write order)

        f32x4 acc[4][2];
        #pragma unroll
        for (int mt = 0; mt < 4; ++mt) {
            acc[mt][0] = (f32x4){b1v0, b1v0, b1v0, b1v0};
            acc[mt][1] = (f32x4){b1v1, b1v1, b1v1, b1v1};
        }

        #pragma unroll
        for (int mt = 0; mt < 4; ++mt) {
            const int e    = ebase + mt * 16 + l15;
            const int srcn = eidx[e];
            const int dstn = eidx[NE + e];
            const int4* xd = (const int4*)(xb + (size_t)dstn * 64);
            const int4* xs = (const int4*)(xb + (size_t)srcn * 64);
            const int4* ep = (const int4*)(eamsg + (size_t)e * 64);
            short8 a0, a1, a2, a3, a4, a5;
            { S8I4 u;
              u.i = xd[quad];     a0 = u.s;
              u.i = xd[quad + 4]; a1 = u.s;
              u.i = xs[quad];     a2 = u.s;
              u.i = xs[quad + 4]; a3 = u.s; }
            if (MODE == 0) {
                S8I4 u;
                u.i = ep[quad];     a4 = u.s;
                u.i = ep[quad + 4]; a5 = u.s;
            } else {
                S8I4 u0, u1;
                u0.i = ep[quad];
                u1.i = ep[quad + 4];
                float v0[8], v1[8], s = 0.f, s2 = 0.f;
                #pragma unroll
                for (int j = 0; j < 8; ++j) {
                    v0[j] = bf2f(u0.s[j]); v1[j] = bf2f(u1.s[j]);
                    s += v0[j] + v1[j];
                    s2 = fmaf(v0[j], v0[j], fmaf(v1[j], v1[j], s2));
                }
                s  += __shfl_xor(s, 16);  s  += __shfl_xor(s, 32);
                s2 += __shfl_xor(s2, 16); s2 += __shfl_xor(s2, 32);
                float mu = s * 0.015625f, var = s2 * 0.015625f - mu * mu;
                float rs = rsqrtf(var + 1e-5f);
                short8 t0, t1;
                #pragma unroll
                for (int j = 0; j < 8; ++j) {
                    t0[j] = f2bf((v0[j] - mu) * rs * lnGv[j] + lnBv[j]);
                    t1[j] = f2bf((v1[j] - mu) * rs * lnGv[8 + j] + lnBv[8 + j]);
                }
                a4 = t0; a5 = t1;
            }
            acc[mt][0] = MFMA(a0, B1[0][0], acc[mt][0]);
            acc[mt][1] = MFMA(a0, B1[0][1], acc[mt][1]);
            acc[mt][0] = MFMA(a1, B1[1][0], acc[mt][0]);
            acc[mt][1] = MFMA(a1, B1[1][1], acc[mt][1]);
            acc[mt][0] = MFMA(a2, B1[2][0], acc[mt][0]);
            acc[mt][1] = MFMA(a2, B1[2][1], acc[mt][1]);
            acc[mt][0] = MFMA(a3, B1[3][0], acc[mt][0]);
            acc[mt][1] = MFMA(a3, B1[3][1], acc[mt][1]);
            acc[mt][0] = MFMA(a4, B1[4][0], acc[mt][0]);
            acc[mt][1] = MFMA(a4, B1[4][1], acc[mt][1]);
            acc[mt][0] = MFMA(a5, B1[5][0], acc[mt][0]);
            acc[mt][1] = MFMA(a5, B1[5][1], acc[mt][1]);
        }

        // relu + C-layout -> h_lds[m][n] (bf16, padded stride)
        #pragma unroll
        for (int mt = 0; mt < 4; ++mt)
            #pragma unroll
            for (int nf = 0; nf < 2; ++nf) {
                int n = wave * 32 + nf * 16 + l15;
                #pragma unroll
                for (int r = 0; r < 4; ++r) {
                    int m = mt * 16 + quad * 4 + r;
                    h_lds[m * HSTR + n] = f2bf(fmaxf(acc[mt][nf][r], 0.f));
                }
            }
        __syncthreads();

        // layer 2: A from h_lds (ds_read_b128), B2 in regs
        f32x4 acc2[4];
        #pragma unroll
        for (int mt = 0; mt < 4; ++mt) acc2[mt] = (f32x4){b2v, b2v, b2v, b2v};
        #pragma unroll
        for (int mt = 0; mt < 4; ++mt) {
            const short* hr = h_lds + (mt * 16 + l15) * HSTR;
            #pragma unroll
            for (int kt = 0; kt < 4; ++kt) {
                S8I4 u; u.i = *(const int4*)(hr + kt * 32 + qoff);
                acc2[mt] = MFMA(u.s, B2[kt], acc2[mt]);
            }
        }

        // store msg bf16 (C-layout scatter; 16 lanes/quad are 32B-contiguous)
        #pragma unroll
        for (int mt = 0; mt < 4; ++mt) {
            int n = wave * 16 + l15;
            #pragma unroll
            for (int r = 0; r < 4; ++r) {
                int m = mt * 16 + quad * 4 + r;
                msgb[(size_t)(ebase + m) * 64 + n] = f2bf(acc2[mt][r]);
            }
        }
    }
}

// ---------------- gather0: x1 = agg+root (fp32); hb = bf16(relu(LN(x1))) ------
__global__ __launch_bounds__(256) void k_gather0(
    const float* __restrict__ xenc, const short* __restrict__ msgb,
    const int* __restrict__ row_ptr, const int* __restrict__ eord,
    const float* __restrict__ wr, const float* __restrict__ g,
    const float* __restrict__ b, const float* __restrict__ tp,
    float* __restrict__ x1, short* __restrict__ hb)
{
    int node = (blockIdx.x * 256 + threadIdx.x) >> 6;
    int lane = threadIdx.x & 63;
    if (node >= NN) return;
    const float* xr = xenc + (size_t)node * 64;
    float root = 0.f;
    #pragma unroll
    for (int k = 0; k < 64; ++k) root = fmaf(xr[k], wr[k * 64 + lane], root);
    const float t = tp[0];
    int beg = row_ptr[node], end = row_ptr[node + 1];
    float den = 0.f, num = 0.f;
    for (int i = beg; i < end; ++i) {
        int e = eord[i];
        float m = bf2f(msgb[(size_t)e * 64 + lane]);
        float ex = __expf(m * t);
        den += ex;
        num = fmaf(m, ex, num);
    }
    float v = root + (den > 0.f ? num / den : 0.f);
    size_t idx = (size_t)node * 64 + lane;
    x1[idx] = v;
    float s = v, s2 = v * v;
    #pragma unroll
    for (int off = 32; off; off >>= 1) { s += __shfl_xor(s, off); s2 += __shfl_xor(s2, off); }
    float mu = s * 0.015625f, var = s2 * 0.015625f - mu * mu;
    float r = rsqrtf(var + 1e-5f);
    hb[idx] = f2bf(fmaxf((v - mu) * r * g[lane] + b[lane], 0.f));
}

// ---------------- gather1: out = x1 + root(hb) + agg(msg1) ----------------
__global__ __launch_bounds__(256) void k_gather1(
    const float* __restrict__ x1, const short* __restrict__ hb,
    const short* __restrict__ msgb,
    const int* __restrict__ row_ptr, const int* __restrict__ eord,
    const float* __restrict__ wr, const float* __restrict__ tp,
    float* __restrict__ out)
{
    int node = (blockIdx.x * 256 + threadIdx.x) >> 6;
    int lane = threadIdx.x & 63;
    if (node >= NN) return;
    const short* hr = hb + (size_t)node * 64;
    float root = 0.f;
    #pragma unroll
    for (int k = 0; k < 64; ++k) root = fmaf(bf2f(hr[k]), wr[k * 64 + lane], root);
    const float t = tp[0];
    int beg = row_ptr[node], end = row_ptr[node + 1];
    float den = 0.f, num = 0.f;
    for (int i = beg; i < end; ++i) {
        int e = eord[i];
        float m = bf2f(msgb[(size_t)e * 64 + lane]);
        float ex = __expf(m * t);
        den += ex;
        num = fmaf(m, ex, num);
    }
    size_t idx = (size_t)node * 64 + lane;
    out[idx] = x1[idx] + root + (den > 0.f ? num / den : 0.f);
}

extern "C" void kernel_launch(void* const* d_in, const int* in_sizes, int n_in,
                              void* d_out, int out_size, void* d_ws, size_t ws_size,
                              hipStream_t stream)
{
    const float* x       = (const float*)d_in[0];
    const int*   eidx    = (const int*)  d_in[1];
    const float* eattr   = (const float*)d_in[2];
    const float* enc_w   = (const float*)d_in[3];
    const float* enc_b   = (const float*)d_in[4];
    const float* enc_g   = (const float*)d_in[5];
    const float* enc_bb  = (const float*)d_in[6];
    const float* eenc_w  = (const float*)d_in[7];
    const float* eenc_b  = (const float*)d_in[8];
    const float* eenc_g  = (const float*)d_in[9];
    const float* eenc_bb = (const float*)d_in[10];
    const float* c0_w1   = (const float*)d_in[11];
    const float* c0_b1   = (const float*)d_in[12];
    const float* c0_w2   = (const float*)d_in[13];
    const float* c0_b2   = (const float*)d_in[14];
    const float* c0_wr   = (const float*)d_in[15];
    const float* c0_t    = (const float*)d_in[16];
    const float* l1_g    = (const float*)d_in[17];
    const float* l1_b    = (const float*)d_in[18];
    const float* l1_eg   = (const float*)d_in[19];
    const float* l1_eb   = (const float*)d_in[20];
    const float* c1_w1   = (const float*)d_in[21];
    const float* c1_b1   = (const float*)d_in[22];
    const float* c1_w2   = (const float*)d_in[23];
    const float* c1_b2   = (const float*)d_in[24];
    const float* c1_wr   = (const float*)d_in[25];
    const float* c1_t    = (const float*)d_in[26];

    const size_t NV = (size_t)NN * 64;
    char* base = (char*)d_ws;
    auto take = [&](size_t bytes) {
        char* p = base;
        base += (bytes + 255) & ~(size_t)255;
        return p;
    };
    float* xenc    = (float*)take(NV * 4);
    float* x1      = (float*)take(NV * 4);
    int*   deg     = (int*)  take(NN * 4);
    int*   row_ptr = (int*)  take((NN + 1) * 4);
    int*   cursor  = (int*)  take(NN * 4);
    int*   eord    = (int*)  take((size_t)NE * 4);
    short* xb      = (short*)take(NV * 2);
    short* hb      = (short*)take(NV * 2);
    short* w1p0    = (short*)take(24576 * 2);
    short* w1p1    = (short*)take(24576 * 2);
    short* w2p0    = (short*)take(8192 * 2);
    short* w2p1    = (short*)take(8192 * 2);
    short* eab     = (short*)take((size_t)NE * 64 * 2);
    short* msgb    = (short*)take((size_t)NE * 64 * 2);
    float* out     = (float*)d_out;

    hipMemsetAsync(deg, 0, NN * sizeof(int), stream);

    k_prep_w  <<<96, 256, 0, stream>>>(c0_w1, c0_w2, c1_w1, c1_w2, w1p0, w2p0, w1p1, w2p1);
    k_node_enc<<<NN / 4, 256, 0, stream>>>(x, enc_w, enc_b, enc_g, enc_bb, xenc, xb);
    k_edge_enc<<<NE / 4, 256, 0, stream>>>(eattr, eenc_w, eenc_b, eenc_g, eenc_bb, eab);
    k_degree  <<<NE / 256, 256, 0, stream>>>(eidx, deg);
    k_scan    <<<1, 1024, 0, stream>>>(deg, row_ptr, cursor);
    k_scatter <<<NE / 256, 256, 0, stream>>>(eidx, cursor, eord);

    k_conv_mfma<0><<<2500, 256, 0, stream>>>(
        xb, eidx, eab, nullptr, nullptr, w1p0, c0_b1, w2p0, c0_b2, msgb);

    k_gather0<<<NN / 4, 256, 0, stream>>>(
        xenc, msgb, row_ptr, eord, c0_wr, l1_g, l1_b, c0_t, x1, hb);

    k_conv_mfma<1><<<2500, 256, 0, stream>>>(
        hb, eidx, msgb, l1_eg, l1_eb, w1p1, c1_b1, w2p1, c1_b2, msgb);

    k_gather1<<<NN / 4, 256, 0, stream>>>(
        x1, hb, msgb, row_ptr, eord, c1_wr, c1_t, out);
}

// Round 5
// 633.398 us; speedup vs baseline: 14.2189x; 1.6422x over previous
//
#include <hip/hip_runtime.h>

#define NN 20000
#define NE 640000
#define NTILES (NE / 64)
#define XSTR 72    // x_lds / a_lds row stride (shorts): 16B-aligned rows, balanced banks
#define HSTR 136   // h_lds row stride (shorts), columns XOR-swizzled by (m&8)

typedef float f32x4 __attribute__((ext_vector_type(4)));
typedef short short8 __attribute__((ext_vector_type(8)));
union S8I4 { int4 i; short8 s; };

#define MFMA(a, b, c) __builtin_amdgcn_mfma_f32_16x16x32_bf16((a), (b), (c), 0, 0, 0)

__device__ __forceinline__ short f2bf(float f) {
    unsigned u = __float_as_uint(f);
    u = (u + 0x7FFFu + ((u >> 16) & 1u)) >> 16;   // RNE
    return (short)u;
}
__device__ __forceinline__ float bf2f(short s) {
    return __uint_as_float(((unsigned)(unsigned short)s) << 16);
}

// ---------------- weight pre-pack ----------------
// W1 pack (B-frag order, frag f = kt*8+nt): rows k>=128 (ea) pre-scaled by LN gamma.
// b1eff[j] = b1[j] + sum_k beta[k]*w1[128+k][j]  (LN beta folded out of the kernel).
// pbenc: eenc_w [16,64] K-padded to 32 in B-frag order (conv0 fused encoder).
__global__ __launch_bounds__(256) void k_prep_w(
    const float* __restrict__ w1a, const float* __restrict__ w2a,
    const float* __restrict__ w1b, const float* __restrict__ w2b,
    const float* __restrict__ eencw,
    const float* __restrict__ g0, const float* __restrict__ be0,  // eenc_g, eenc_bb
    const float* __restrict__ g1, const float* __restrict__ be1,  // l1_eg, l1_eb
    const float* __restrict__ b1a, const float* __restrict__ b1b,
    short* __restrict__ p1a, short* __restrict__ p2a,
    short* __restrict__ p1b, short* __restrict__ p2b,
    short* __restrict__ pbenc, float* __restrict__ b1ea, float* __restrict__ b1eb)
{
    int idx = blockIdx.x * 256 + threadIdx.x;      // grid 96*256 = 24576
    {
        int f = idx >> 9, l = (idx >> 3) & 63, j = idx & 7;
        int kt = f >> 3, nt = f & 7;
        int k = kt * 32 + ((l >> 4) << 3) + j;
        int n = (nt << 4) + (l & 15);
        float sa = (k >= 128) ? g0[k - 128] : 1.f;
        float sb = (k >= 128) ? g1[k - 128] : 1.f;
        p1a[idx] = f2bf(sa * w1a[k * 128 + n]);
        p1b[idx] = f2bf(sb * w1b[k * 128 + n]);
    }
    if (idx < 8192) {
        int f = idx >> 9, l = (idx >> 3) & 63, j = idx & 7;
        int kt = f >> 2, nt = f & 3;
        int k = kt * 32 + ((l >> 4) << 3) + j;
        int n = (nt << 4) + (l & 15);
        p2a[idx] = f2bf(w2a[k * 64 + n]);
        p2b[idx] = f2bf(w2b[k * 64 + n]);
    }
    if (idx < 2048) {   // encoder B: 4 frags (nt=f), K padded 16->32
        int f = idx >> 9, l = (idx >> 3) & 63, j = idx & 7;
        int k = ((l >> 4) << 3) + j;
        int n = (f << 4) + (l & 15);
        pbenc[idx] = (k < 16) ? f2bf(eencw[k * 64 + n]) : (short)0;
    }
    if (idx < 256) {
        int conv = idx >> 7, j = idx & 127;
        const float* w1  = conv ? w1b : w1a;
        const float* bet = conv ? be1 : be0;
        float s = conv ? b1b[j] : b1a[j];
        for (int k = 0; k < 64; ++k) s = fmaf(bet[k], w1[(128 + k) * 128 + j], s);
        (conv ? b1eb : b1ea)[j] = s;
    }
}

// ---------------- node encoder: xenc fp32 + xb bf16 ----------------
__global__ __launch_bounds__(256) void k_node_enc(
    const float* __restrict__ x, const float* __restrict__ w,
    const float* __restrict__ b, const float* __restrict__ g,
    const float* __restrict__ bb, float* __restrict__ out, short* __restrict__ outb)
{
    int node = (blockIdx.x * 256 + threadIdx.x) >> 6;
    int lane = threadIdx.x & 63;
    if (node >= NN) return;
    const float* xr = x + (size_t)node * 96;
    float acc = b[lane];
    #pragma unroll
    for (int k = 0; k < 96; ++k) acc = fmaf(xr[k], w[k * 64 + lane], acc);
    float s = acc, s2 = acc * acc;
    #pragma unroll
    for (int off = 32; off; off >>= 1) { s += __shfl_xor(s, off); s2 += __shfl_xor(s2, off); }
    float mu = s * 0.015625f, var = s2 * 0.015625f - mu * mu;
    float r = rsqrtf(var + 1e-5f);
    float v = (acc - mu) * r * g[lane] + bb[lane];
    size_t idx = (size_t)node * 64 + lane;
    out[idx] = v;
    outb[idx] = f2bf(v);
}

// ---------------- CSR build (+ permuted src/dst/attr-id arrays) ----------------
__global__ __launch_bounds__(256) void k_degree(
    const int* __restrict__ eidx, int* __restrict__ deg)
{
    int e = blockIdx.x * 256 + threadIdx.x;
    if (e < NE) atomicAdd(&deg[eidx[NE + e]], 1);
}

__global__ __launch_bounds__(1024) void k_scan(
    const int* __restrict__ deg, int* __restrict__ row_ptr, int* __restrict__ cursor)
{
    __shared__ int sums[1024];
    const int T = 1024, CHUNK = (NN + 1023) / 1024;
    int tid = threadIdx.x;
    int base = tid * CHUNK;
    int local = 0;
    for (int i = 0; i < CHUNK; ++i) { int idx = base + i; if (idx < NN) local += deg[idx]; }
    sums[tid] = local;
    __syncthreads();
    for (int off = 1; off < T; off <<= 1) {
        int v = (tid >= off) ? sums[tid - off] : 0;
        __syncthreads();
        sums[tid] += v;
        __syncthreads();
    }
    int run = (tid == 0) ? 0 : sums[tid - 1];
    for (int i = 0; i < CHUNK; ++i) {
        int idx = base + i;
        if (idx < NN) { row_ptr[idx] = run; cursor[idx] = run; run += deg[idx]; }
    }
    if (tid == T - 1) row_ptr[NN] = run;
}

__global__ __launch_bounds__(256) void k_scatter(
    const int* __restrict__ eidx, int* __restrict__ cursor,
    int* __restrict__ psrc, int* __restrict__ pdst, int* __restrict__ peid)
{
    int e = blockIdx.x * 256 + threadIdx.x;
    if (e < NE) {
        int s = eidx[e], d = eidx[NE + e];
        int p = atomicAdd(&cursor[d], 1);
        psrc[p] = s; pdst[p] = d; peid[p] = e;
    }
}

// ---------------- MFMA edge conv (slot order; LDS-staged A) ----------------
// Block = 64 edge slots, 4 waves. Per tile:
//  stage x_dst/x_src rows -> x_lds (block-coop).
//  MODE0: fused edge encoder (K-padded MFMA from attr) -> a_lds (raw enc).
//  MODE1: stream msgb rows -> a_lds (raw msg).
//  stats pass: per-row LN -> a_lds := (v-mu)*rs   (gamma/beta folded into W1/b1eff).
//  layer1 MFMA (frags from LDS) -> h_lds (relu, bf16, XOR-swizzled cols).
//  layer2 MFMA -> msgb[slot] (sequential rows, bf16).
template <int MODE>
__global__ __launch_bounds__(256, 3) void k_conv_mfma(
    const short* __restrict__ xb,
    const int* __restrict__ psrc, const int* __restrict__ pdst,
    const int* __restrict__ peid,                      // MODE0
    const float* __restrict__ eattr,                   // MODE0
    const short* __restrict__ pbenc,                   // MODE0
    const float* __restrict__ encb,                    // MODE0 (eenc_b)
    const short* __restrict__ w1p, const float* __restrict__ b1e,
    const short* __restrict__ w2p, const float* __restrict__ b2,
    short* __restrict__ msgb)
{
    __shared__ short x_lds[128 * XSTR];
    __shared__ short a_lds[64 * XSTR];
    __shared__ short h_lds[64 * HSTR];
    const int tid  = threadIdx.x;
    const int wave = tid >> 6;
    const int lane = tid & 63;
    const int quad = lane >> 4;
    const int l15  = lane & 15;
    const int qoff = quad * 8;

    short8 B1[6][2], B2[4], Benc;
    {
        const int4* p = (const int4*)w1p;
        #pragma unroll
        for (int kt = 0; kt < 6; ++kt)
            #pragma unroll
            for (int nf = 0; nf < 2; ++nf) {
                S8I4 u; u.i = p[(kt * 8 + wave * 2 + nf) * 64 + lane];
                B1[kt][nf] = u.s;
            }
        const int4* q = (const int4*)w2p;
        #pragma unroll
        for (int kt = 0; kt < 4; ++kt) { S8I4 u; u.i = q[(kt * 4 + wave) * 64 + lane]; B2[kt] = u.s; }
        if (MODE == 0) { S8I4 u; u.i = ((const int4*)pbenc)[wave * 64 + lane]; Benc = u.s; }
    }
    const float b1v0 = b1e[wave * 32 + l15];
    const float b1v1 = b1e[wave * 32 + 16 + l15];
    const float b2v  = b2[wave * 16 + l15];
    const float encbv = (MODE == 0) ? encb[wave * 16 + l15] : 0.f;

    for (int t = blockIdx.x; t < NTILES; t += gridDim.x) {
        const int ebase = t * 64;
        __syncthreads();   // protect LDS from previous iteration's readers

        // ---- stage x_dst (rows 0..63) and x_src (rows 64..127) ----
        #pragma unroll
        for (int it = 0; it < 4; ++it) {
            int item = it * 256 + tid;            // 0..1023
            int row = item >> 3, c = item & 7;
            int slot = ebase + (row & 63);
            int node = (row < 64) ? pdst[slot] : psrc[slot];
            *(int4*)(x_lds + row * XSTR + c * 8) =
                *(const int4*)(xb + (size_t)node * 64 + c * 8);
        }
        // ---- stage ea source into a_lds ----
        if (MODE == 1) {
            #pragma unroll
            for (int it = 0; it < 2; ++it) {
                int item = it * 256 + tid;        // 0..511
                int row = item >> 3, c = item & 7;
                *(int4*)(a_lds + row * XSTR + c * 8) =
                    *(const int4*)(msgb + (size_t)(ebase + row) * 64 + c * 8);
            }
        } else {
            #pragma unroll
            for (int mt = 0; mt < 4; ++mt) {
                int slot = ebase + mt * 16 + l15;
                short8 ae = {0, 0, 0, 0, 0, 0, 0, 0};
                if (quad < 2) {
                    int row = peid[slot];
                    const float* ap = eattr + (size_t)row * 16 + qoff;
                    float4 u0 = *(const float4*)ap;
                    float4 u1 = *(const float4*)(ap + 4);
                    ae[0] = f2bf(u0.x); ae[1] = f2bf(u0.y); ae[2] = f2bf(u0.z); ae[3] = f2bf(u0.w);
                    ae[4] = f2bf(u1.x); ae[5] = f2bf(u1.y); ae[6] = f2bf(u1.z); ae[7] = f2bf(u1.w);
                }
                f32x4 ac = {encbv, encbv, encbv, encbv};
                ac = MFMA(ae, Benc, ac);
                #pragma unroll
                for (int r = 0; r < 4; ++r)
                    a_lds[(mt * 16 + quad * 4 + r) * XSTR + wave * 16 + l15] = f2bf(ac[r]);
            }
        }
        __syncthreads();

        // ---- LN stats + normalize in place: a := (v - mu) * rsqrt(var+eps) ----
        {
            int m = tid >> 2, q = tid & 3;
            short* rp = a_lds + m * XSTR + q * 16;
            S8I4 u0, u1;
            u0.i = *(int4*)rp;
            u1.i = *(int4*)(rp + 8);
            float v[16], s = 0.f, s2 = 0.f;
            #pragma unroll
            for (int j = 0; j < 8; ++j) { v[j] = bf2f(u0.s[j]); v[8 + j] = bf2f(u1.s[j]); }
            #pragma unroll
            for (int j = 0; j < 16; ++j) { s += v[j]; s2 = fmaf(v[j], v[j], s2); }
            s  += __shfl_xor(s, 1);  s  += __shfl_xor(s, 2);
            s2 += __shfl_xor(s2, 1); s2 += __shfl_xor(s2, 2);
            float mu = s * 0.015625f, var = s2 * 0.015625f - mu * mu;
            float rs = rsqrtf(var + 1e-5f);
            S8I4 w0, w1u;
            #pragma unroll
            for (int j = 0; j < 8; ++j) {
                w0.s[j]  = f2bf((v[j] - mu) * rs);
                w1u.s[j] = f2bf((v[8 + j] - mu) * rs);
            }
            *(int4*)rp       = w0.i;
            *(int4*)(rp + 8) = w1u.i;
        }
        __syncthreads();

        // ---- layer 1 ----
        f32x4 acc[4][2];
        #pragma unroll
        for (int mt = 0; mt < 4; ++mt) {
            acc[mt][0] = (f32x4){b1v0, b1v0, b1v0, b1v0};
            acc[mt][1] = (f32x4){b1v1, b1v1, b1v1, b1v1};
        }
        #pragma unroll
        for (int mt = 0; mt < 4; ++mt) {
            const short* xr = x_lds + (mt * 16 + l15) * XSTR;
            const short* sr = xr + 64 * XSTR;
            const short* ar = a_lds + (mt * 16 + l15) * XSTR;
            S8I4 a0, a1, a2, a3, a4, a5;
            a0.i = *(const int4*)(xr + qoff);
            a1.i = *(const int4*)(xr + 32 + qoff);
            a2.i = *(const int4*)(sr + qoff);
            a3.i = *(const int4*)(sr + 32 + qoff);
            a4.i = *(const int4*)(ar + qoff);
            a5.i = *(const int4*)(ar + 32 + qoff);
            acc[mt][0] = MFMA(a0.s, B1[0][0], acc[mt][0]);
            acc[mt][1] = MFMA(a0.s, B1[0][1], acc[mt][1]);
            acc[mt][0] = MFMA(a1.s, B1[1][0], acc[mt][0]);
            acc[mt][1] = MFMA(a1.s, B1[1][1], acc[mt][1]);
            acc[mt][0] = MFMA(a2.s, B1[2][0], acc[mt][0]);
            acc[mt][1] = MFMA(a2.s, B1[2][1], acc[mt][1]);
            acc[mt][0] = MFMA(a3.s, B1[3][0], acc[mt][0]);
            acc[mt][1] = MFMA(a3.s, B1[3][1], acc[mt][1]);
            acc[mt][0] = MFMA(a4.s, B1[4][0], acc[mt][0]);
            acc[mt][1] = MFMA(a4.s, B1[4][1], acc[mt][1]);
            acc[mt][0] = MFMA(a5.s, B1[5][0], acc[mt][0]);
            acc[mt][1] = MFMA(a5.s, B1[5][1], acc[mt][1]);
        }
        __syncthreads();   // a_lds reads done before h writes (layouts overlap in time)

        // ---- relu -> h_lds (bf16, XOR-swizzled columns: conflict-free writes) ----
        #pragma unroll
        for (int mt = 0; mt < 4; ++mt)
            #pragma unroll
            for (int nf = 0; nf < 2; ++nf) {
                int n = wave * 32 + nf * 16 + l15;
                #pragma unroll
                for (int r = 0; r < 4; ++r) {
                    int m = mt * 16 + quad * 4 + r;
                    h_lds[m * HSTR + (n ^ (m & 8))] = f2bf(fmaxf(acc[mt][nf][r], 0.f));
                }
            }
        __syncthreads();

        // ---- layer 2 ----
        f32x4 acc2[4];
        #pragma unroll
        for (int mt = 0; mt < 4; ++mt) acc2[mt] = (f32x4){b2v, b2v, b2v, b2v};
        #pragma unroll
        for (int mt = 0; mt < 4; ++mt) {
            int m = mt * 16 + l15;
            const short* hr = h_lds + m * HSTR;
            int sw = m & 8;
            #pragma unroll
            for (int kt = 0; kt < 4; ++kt) {
                S8I4 u; u.i = *(const int4*)(hr + ((kt * 32 + qoff) ^ sw));
                acc2[mt] = MFMA(u.s, B2[kt], acc2[mt]);
            }
        }
        // ---- store msg (sequential slot rows) ----
        #pragma unroll
        for (int mt = 0; mt < 4; ++mt) {
            int n = wave * 16 + l15;
            #pragma unroll
            for (int r = 0; r < 4; ++r) {
                int m = mt * 16 + quad * 4 + r;
                msgb[(size_t)(ebase + m) * 64 + n] = f2bf(acc2[mt][r]);
            }
        }
    }
}

// ---------------- gather0: x1 = agg+root (fp32); hb = bf16(relu(LN(x1))) ------
__global__ __launch_bounds__(256) void k_gather0(
    const float* __restrict__ xenc, const short* __restrict__ msgb,
    const int* __restrict__ row_ptr,
    const float* __restrict__ wr, const float* __restrict__ g,
    const float* __restrict__ b, const float* __restrict__ tp,
    float* __restrict__ x1, short* __restrict__ hb)
{
    int node = (blockIdx.x * 256 + threadIdx.x) >> 6;
    int lane = threadIdx.x & 63;
    if (node >= NN) return;
    const float* xr = xenc + (size_t)node * 64;
    float root = 0.f;
    #pragma unroll
    for (int k = 0; k < 64; ++k) root = fmaf(xr[k], wr[k * 64 + lane], root);
    const float t = tp[0];
    int beg = row_ptr[node], end = row_ptr[node + 1];
    float den = 0.f, num = 0.f;
    for (int i = beg; i < end; ++i) {
        float m = bf2f(msgb[(size_t)i * 64 + lane]);
        float ex = __expf(m * t);
        den += ex;
        num = fmaf(m, ex, num);
    }
    float v = root + (den > 0.f ? num / den : 0.f);
    size_t idx = (size_t)node * 64 + lane;
    x1[idx] = v;
    float s = v, s2 = v * v;
    #pragma unroll
    for (int off = 32; off; off >>= 1) { s += __shfl_xor(s, off); s2 += __shfl_xor(s2, off); }
    float mu = s * 0.015625f, var = s2 * 0.015625f - mu * mu;
    float r = rsqrtf(var + 1e-5f);
    hb[idx] = f2bf(fmaxf((v - mu) * r * g[lane] + b[lane], 0.f));
}

// ---------------- gather1: out = x1 + root(hb) + agg(msg1) ----------------
__global__ __launch_bounds__(256) void k_gather1(
    const float* __restrict__ x1, const short* __restrict__ hb,
    const short* __restrict__ msgb, const int* __restrict__ row_ptr,
    const float* __restrict__ wr, const float* __restrict__ tp,
    float* __restrict__ out)
{
    int node = (blockIdx.x * 256 + threadIdx.x) >> 6;
    int lane = threadIdx.x & 63;
    if (node >= NN) return;
    const short* hr = hb + (size_t)node * 64;
    float root = 0.f;
    #pragma unroll
    for (int k = 0; k < 64; ++k) root = fmaf(bf2f(hr[k]), wr[k * 64 + lane], root);
    const float t = tp[0];
    int beg = row_ptr[node], end = row_ptr[node + 1];
    float den = 0.f, num = 0.f;
    for (int i = beg; i < end; ++i) {
        float m = bf2f(msgb[(size_t)i * 64 + lane]);
        float ex = __expf(m * t);
        den += ex;
        num = fmaf(m, ex, num);
    }
    size_t idx = (size_t)node * 64 + lane;
    out[idx] = x1[idx] + root + (den > 0.f ? num / den : 0.f);
}

extern "C" void kernel_launch(void* const* d_in, const int* in_sizes, int n_in,
                              void* d_out, int out_size, void* d_ws, size_t ws_size,
                              hipStream_t stream)
{
    const float* x       = (const float*)d_in[0];
    const int*   eidx    = (const int*)  d_in[1];
    const float* eattr   = (const float*)d_in[2];
    const float* enc_w   = (const float*)d_in[3];
    const float* enc_b   = (const float*)d_in[4];
    const float* enc_g   = (const float*)d_in[5];
    const float* enc_bb  = (const float*)d_in[6];
    const float* eenc_w  = (const float*)d_in[7];
    const float* eenc_b  = (const float*)d_in[8];
    const float* eenc_g  = (const float*)d_in[9];
    const float* eenc_bb = (const float*)d_in[10];
    const float* c0_w1   = (const float*)d_in[11];
    const float* c0_b1   = (const float*)d_in[12];
    const float* c0_w2   = (const float*)d_in[13];
    const float* c0_b2   = (const float*)d_in[14];
    const float* c0_wr   = (const float*)d_in[15];
    const float* c0_t    = (const float*)d_in[16];
    const float* l1_g    = (const float*)d_in[17];
    const float* l1_b    = (const float*)d_in[18];
    const float* l1_eg   = (const float*)d_in[19];
    const float* l1_eb   = (const float*)d_in[20];
    const float* c1_w1   = (const float*)d_in[21];
    const float* c1_b1   = (const float*)d_in[22];
    const float* c1_w2   = (const float*)d_in[23];
    const float* c1_b2   = (const float*)d_in[24];
    const float* c1_wr   = (const float*)d_in[25];
    const float* c1_t    = (const float*)d_in[26];

    const size_t NV = (size_t)NN * 64;
    char* base = (char*)d_ws;
    auto take = [&](size_t bytes) {
        char* p = base;
        base += (bytes + 255) & ~(size_t)255;
        return p;
    };
    float* xenc    = (float*)take(NV * 4);
    float* x1      = (float*)take(NV * 4);
    int*   deg     = (int*)  take(NN * 4);
    int*   row_ptr = (int*)  take((NN + 1) * 4);
    int*   cursor  = (int*)  take(NN * 4);
    int*   psrc    = (int*)  take((size_t)NE * 4);
    int*   pdst    = (int*)  take((size_t)NE * 4);
    int*   peid    = (int*)  take((size_t)NE * 4);
    short* xb      = (short*)take(NV * 2);
    short* hb      = (short*)take(NV * 2);
    short* w1p0    = (short*)take(24576 * 2);
    short* w1p1    = (short*)take(24576 * 2);
    short* w2p0    = (short*)take(8192 * 2);
    short* w2p1    = (short*)take(8192 * 2);
    short* pbenc   = (short*)take(2048 * 2);
    float* b1e0    = (float*)take(128 * 4);
    float* b1e1    = (float*)take(128 * 4);
    short* msgb    = (short*)take((size_t)NE * 64 * 2);
    float* out     = (float*)d_out;

    hipMemsetAsync(deg, 0, NN * sizeof(int), stream);

    k_prep_w  <<<96, 256, 0, stream>>>(c0_w1, c0_w2, c1_w1, c1_w2, eenc_w,
                                       eenc_g, eenc_bb, l1_eg, l1_eb, c0_b1, c1_b1,
                                       w1p0, w2p0, w1p1, w2p1, pbenc, b1e0, b1e1);
    k_node_enc<<<NN / 4, 256, 0, stream>>>(x, enc_w, enc_b, enc_g, enc_bb, xenc, xb);
    k_degree  <<<NE / 256, 256, 0, stream>>>(eidx, deg);
    k_scan    <<<1, 1024, 0, stream>>>(deg, row_ptr, cursor);
    k_scatter <<<NE / 256, 256, 0, stream>>>(eidx, cursor, psrc, pdst, peid);

    k_conv_mfma<0><<<768, 256, 0, stream>>>(
        xb, psrc, pdst, peid, eattr, pbenc, eenc_b,
        w1p0, b1e0, w2p0, c0_b2, msgb);

    k_gather0<<<NN / 4, 256, 0, stream>>>(
        xenc, msgb, row_ptr, c0_wr, l1_g, l1_b, c0_t, x1, hb);

    k_conv_mfma<1><<<768, 256, 0, stream>>>(
        hb, psrc, pdst, nullptr, nullptr, nullptr, nullptr,
        w1p1, b1e1, w2p1, c1_b2, msgb);

    k_gather1<<<NN / 4, 256, 0, stream>>>(
        x1, hb, msgb, row_ptr, c1_wr, c1_t, out);
}